// Round 11
// baseline (131.298 us; speedup 1.0000x reference)
//
#include <hip/hip_runtime.h>
#include <hip/hip_bf16.h>

#define LL   2048
#define BB   4
#define DD   512
#define HH   8
#define DKK  64
#define WBAND 12
#define NBAND 25   // 2*WBAND+1

typedef __attribute__((ext_vector_type(8))) short  bf16x8;
typedef __attribute__((ext_vector_type(4))) float  f32x4;

#define WOUT_F4    4194304   // B*L*L/4 total f32x4 in wout
#define ZSPLIT_F4  2621440   // f4 zeroed by proj's zero blocks (40 MB)
// scorez zero blocks cover [ZSPLIT_F4, WOUT_F4) = 1572864 f4 (24 MB)

static __device__ __forceinline__ float bf2f(unsigned short u) {
    union { unsigned int i; float f; } c; c.i = ((unsigned int)u) << 16; return c.f;
}
// manual RNE (epilogue, cold path)
static __device__ __forceinline__ unsigned short f2bf(float f) {
    union { float f; unsigned int i; } c; c.f = f;
    unsigned int x = c.i;
    return (unsigned short)((x + 0x7fffu + ((x >> 16) & 1u)) >> 16);
}
// compiler-fused cvt (hot staging path; pairs become v_cvt_pk_bf16_f32)
static __device__ __forceinline__ unsigned short f2bf_rn(float f) {
    __hip_bfloat16 h = __float2bfloat16(f);
    return reinterpret_cast<unsigned short&>(h);
}
static __device__ __forceinline__ bf16x8 pack8(float4 x0, float4 x1) {
    bf16x8 r;
    r[0] = (short)f2bf_rn(x0.x); r[1] = (short)f2bf_rn(x0.y);
    r[2] = (short)f2bf_rn(x0.z); r[3] = (short)f2bf_rn(x0.w);
    r[4] = (short)f2bf_rn(x1.x); r[5] = (short)f2bf_rn(x1.y);
    r[6] = (short)f2bf_rn(x1.z); r[7] = (short)f2bf_rn(x1.w);
    return r;
}

// ---------------------------------------------------------------------------
// proj: Out[b,h,l,dk] = ((X @ Wm^T)[m,n] + bias[n]) * scale.
// Compute blocks: blockIdx.x < 64 (128x128 tile, BK=64, XOR-swizzled LDS).
// Zero blocks:    blockIdx.x >= 64 — dedicated writers zeroing the first
// 40 MB of wout (block specialization: store-stalled waves don't block
// compute waves; TLP hides the capped d_out write drain).
// grid (64+32, 4, 2).
// ---------------------------------------------------------------------------
__global__ __launch_bounds__(256) void proj_mfma(
    const float* __restrict__ Xq, const float* __restrict__ Xk,
    const float* __restrict__ Wqf, const float* __restrict__ Wkf,
    const float* __restrict__ bq, const float* __restrict__ bk,
    unsigned short* __restrict__ Qh, unsigned short* __restrict__ Kh,
    float* __restrict__ wout)
{
    __shared__ unsigned short Asm[128 * 64];
    __shared__ unsigned short Bsm[128 * 64];

    const int t = threadIdx.x;

    if (blockIdx.x >= 64) {                 // ---- zero block ----
        const int zb  = (blockIdx.z * 4 + blockIdx.y) * 32 + (blockIdx.x - 64); // 0..255
        const int gid = zb * 256 + t;                                           // 0..65535
        const f32x4 zz = {0.f, 0.f, 0.f, 0.f};
#pragma unroll
        for (int i = 0; i < 40; ++i)        // 256 blocks * 40 f4/thread = 2621440 f4
            *(f32x4*)&wout[((size_t)gid + (size_t)i * 65536) * 4] = zz;
        return;
    }

    const int which = blockIdx.z;
    const float* X   = which ? Xk  : Xq;
    const float* Wm  = which ? Wkf : Wqf;
    const float* bias = which ? bk : bq;
    unsigned short* Out = which ? Kh : Qh;
    const float scale   = which ? 1.0f : 0.125f;

    const int w  = t >> 6;
    const int l  = t & 63;
    const int wr = w >> 1;
    const int wc = w & 1;
    const int mb = blockIdx.x * 128;
    const int nb = blockIdx.y * 128;
    const int lr = l & 15;
    const int lk = (l >> 4) * 8;

    int srow[4], scol[4], sswz[4];
#pragma unroll
    for (int i = 0; i < 4; ++i) {
        const int flat = t + i * 256;        // 0..1023
        srow[i] = flat >> 3;                 // 0..127
        scol[i] = (flat & 7) * 8;            // 0..56 (elements)
        sswz[i] = (srow[i] * 64 + scol[i]) ^ ((srow[i] & 7) << 3);
    }

    float4 ra[4][2], rb[4][2];
#pragma unroll
    for (int i = 0; i < 4; ++i) {
        const float* pa = &X [(size_t)(mb + srow[i]) * DD + scol[i]];
        const float* pb = &Wm[(size_t)(nb + srow[i]) * DD + scol[i]];
        ra[i][0] = *(const float4*)pa; ra[i][1] = *(const float4*)(pa + 4);
        rb[i][0] = *(const float4*)pb; rb[i][1] = *(const float4*)(pb + 4);
    }

    f32x4 acc[4][4] = {};

    for (int k0 = 0; k0 < DD; k0 += 64) {
        __syncthreads();
#pragma unroll
        for (int i = 0; i < 4; ++i) {
            *(bf16x8*)&Asm[sswz[i]] = pack8(ra[i][0], ra[i][1]);
            *(bf16x8*)&Bsm[sswz[i]] = pack8(rb[i][0], rb[i][1]);
        }
        if (k0 + 64 < DD) {
#pragma unroll
            for (int i = 0; i < 4; ++i) {
                const float* pa = &X [(size_t)(mb + srow[i]) * DD + k0 + 64 + scol[i]];
                const float* pb = &Wm[(size_t)(nb + srow[i]) * DD + k0 + 64 + scol[i]];
                ra[i][0] = *(const float4*)pa; ra[i][1] = *(const float4*)(pa + 4);
                rb[i][0] = *(const float4*)pb; rb[i][1] = *(const float4*)(pb + 4);
            }
        }
        __syncthreads();

#pragma unroll
        for (int kk = 0; kk < 64; kk += 32) {
            bf16x8 af[4], bfr[4];
#pragma unroll
            for (int mi = 0; mi < 4; ++mi) {
                const int row = wr * 64 + 16 * mi + lr;
                af[mi] = *(const bf16x8*)&Asm[(row * 64 + kk + lk) ^ ((row & 7) << 3)];
            }
#pragma unroll
            for (int ni = 0; ni < 4; ++ni) {
                const int row = wc * 64 + 16 * ni + lr;
                bfr[ni] = *(const bf16x8*)&Bsm[(row * 64 + kk + lk) ^ ((row & 7) << 3)];
            }
#pragma unroll
            for (int mi = 0; mi < 4; ++mi)
#pragma unroll
                for (int ni = 0; ni < 4; ++ni)
                    acc[mi][ni] = __builtin_amdgcn_mfma_f32_16x16x32_bf16(
                        af[mi], bfr[ni], acc[mi][ni], 0, 0, 0);
        }
    }

#pragma unroll
    for (int ni = 0; ni < 4; ++ni) {
        const int n  = nb + wc * 64 + 16 * ni + lr;
        const int h  = n >> 6;
        const int dk = n & 63;
        const float bs = bias[n];
#pragma unroll
        for (int mi = 0; mi < 4; ++mi)
#pragma unroll
            for (int j = 0; j < 4; ++j) {
                const int m    = mb + wr * 64 + 16 * mi + (l >> 4) * 4 + j;
                const int lseq = m >> 2;
                const int bidx = m & 3;
                Out[(((size_t)(bidx * HH + h)) * LL + lseq) * DKK + dk] =
                    f2bf((acc[mi][ni][j] + bs) * scale);
            }
    }
}

// ---------------------------------------------------------------------------
// scorez: Z[bh,q] = sum_k exp( Qh[bh,q] . Kh[bh,k] )   (Q pre-scaled by 1/8)
// Compute blocks: blockIdx.x < 32. Zero blocks: blockIdx.x >= 32 zero the
// remaining 24 MB of wout. grid (32+8, 32).
// ---------------------------------------------------------------------------
__global__ __launch_bounds__(256) void scorez_mfma(
    const unsigned short* __restrict__ Qh, const unsigned short* __restrict__ Kh,
    float* __restrict__ Z, float* __restrict__ wout)
{
    __shared__ float Zp[4][64];
    const int t = threadIdx.x;

    if (blockIdx.x >= 32) {                 // ---- zero block ----
        const int zb  = blockIdx.y * 8 + (blockIdx.x - 32);   // 0..255
        const int gid = zb * 256 + t;                          // 0..65535
        const f32x4 zz = {0.f, 0.f, 0.f, 0.f};
#pragma unroll
        for (int i = 0; i < 24; ++i)        // 256 blocks * 24 f4/thread = 1572864 f4
            *(f32x4*)&wout[((size_t)ZSPLIT_F4 + (size_t)gid + (size_t)i * 65536) * 4] = zz;
        return;
    }

    const int w  = t >> 6;
    const int l  = t & 63;
    const int bh = blockIdx.y;
    const int qb = blockIdx.x * 64;
    const int lr = l & 15;
    const int lk = (l >> 4) * 8;
    const unsigned short* Qp = Qh + (size_t)bh * LL * DKK;
    const unsigned short* Kp = Kh + (size_t)bh * LL * DKK;

    bf16x8 qa[4][2];
#pragma unroll
    for (int r = 0; r < 4; ++r)
#pragma unroll
        for (int s = 0; s < 2; ++s)
            qa[r][s] = *(const bf16x8*)&Qp[(size_t)(qb + 16 * r + lr) * DKK + 32 * s + lk];

    float zacc[4][4] = {};
    const int k0 = w * 512;
    for (int kt = k0; kt < k0 + 512; kt += 16) {
        const bf16x8 kb0 = *(const bf16x8*)&Kp[(size_t)(kt + lr) * DKK + lk];
        const bf16x8 kb1 = *(const bf16x8*)&Kp[(size_t)(kt + lr) * DKK + 32 + lk];
#pragma unroll
        for (int r = 0; r < 4; ++r) {
            f32x4 acc = {0.f, 0.f, 0.f, 0.f};
            acc = __builtin_amdgcn_mfma_f32_16x16x32_bf16(qa[r][0], kb0, acc, 0, 0, 0);
            acc = __builtin_amdgcn_mfma_f32_16x16x32_bf16(qa[r][1], kb1, acc, 0, 0, 0);
#pragma unroll
            for (int j = 0; j < 4; ++j)
                zacc[r][j] += __expf(acc[j]);
        }
    }

#pragma unroll
    for (int m = 8; m >= 1; m >>= 1)
#pragma unroll
        for (int r = 0; r < 4; ++r)
#pragma unroll
            for (int j = 0; j < 4; ++j)
                zacc[r][j] += __shfl_xor(zacc[r][j], m, 64);

    if (lr == 0) {
#pragma unroll
        for (int r = 0; r < 4; ++r)
#pragma unroll
            for (int j = 0; j < 4; ++j)
                Zp[w][16 * r + (l >> 4) * 4 + j] = zacc[r][j];
    }
    __syncthreads();
    if (t < 64)
        Z[(size_t)bh * LL + qb + t] = Zp[0][t] + Zp[1][t] + Zp[2][t] + Zp[3][t];
}

// ---------------------------------------------------------------------------
// weights: one WAVE per (b,q): band weights -> wgtbuf + scatter into the
// (already-zeroed) dense wout row.
// ---------------------------------------------------------------------------
__global__ __launch_bounds__(256) void weights_kernel(
    const unsigned short* __restrict__ Qh, const unsigned short* __restrict__ Kh,
    const float* __restrict__ Z, float* __restrict__ wgtbuf,
    float* __restrict__ wout)
{
    const int t = threadIdx.x;
    const int w = t >> 6;
    const int l = t & 63;
    const int idx = blockIdx.x * 4 + w;       // idx = b*L + q
    const int b = idx >> 11;
    const int q = idx & 2047;
    const int h = l >> 3;
    const int jslot = l & 7;

    bf16x8 qv[8];
    {
        const bf16x8* qp = (const bf16x8*)&Qh[(((size_t)b * HH + h) * LL + q) * DKK];
#pragma unroll
        for (int i = 0; i < 8; ++i) qv[i] = qp[i];
    }
    const float zinv = 1.0f / Z[((size_t)b * HH + h) * LL + q];

    float e[4];
#pragma unroll
    for (int c = 0; c < 4; ++c) {
        const int j = jslot + 8 * c;
        const int k = q - WBAND + j;
        float a = 0.f;
        if (j < NBAND && k >= 0 && k < LL) {
            const bf16x8* kp = (const bf16x8*)&Kh[(((size_t)b * HH + h) * LL + k) * DKK];
            float s = 0.f;
#pragma unroll
            for (int i = 0; i < 8; ++i) {
                const bf16x8 ka = kp[i];
#pragma unroll
                for (int ee = 0; ee < 8; ++ee)
                    s += bf2f((unsigned short)qv[i][ee]) * bf2f((unsigned short)ka[ee]);
            }
            a = __expf(s) * zinv;
        }
        e[c] = a;
    }

#pragma unroll
    for (int m = 8; m <= 32; m <<= 1)
#pragma unroll
        for (int c = 0; c < 4; ++c)
            e[c] += __shfl_xor(e[c], m, 64);

    float att[4];
    float part = 0.f;
#pragma unroll
    for (int c = 0; c < 4; ++c) {
        const int j = jslot + 8 * c;
        const float dd = (float)(j - WBAND);
        att[c] = (j < NBAND) ? e[c] * __expf(-0.5f * dd * dd) : 0.f;
        part += att[c];
    }
#pragma unroll
    for (int m = 1; m <= 4; m <<= 1)
        part += __shfl_xor(part, m, 64);
    const float winv = 1.0f / part;

    if (h == 0) {
        float* wrow = &wout[((size_t)b * LL + q) * LL];
#pragma unroll
        for (int c = 0; c < 4; ++c) {
            const int j = jslot + 8 * c;
            if (j < NBAND) {
                const float wv = att[c] * winv;
                wgtbuf[(size_t)idx * 32 + j] = wv;
                const int k = q - WBAND + j;
                if (k >= 0 && k < LL) wrow[k] = wv;
            }
        }
    }
}

// ---------------------------------------------------------------------------
// out: grid (L/8, B). Register sliding window over v; plain stores.
// ---------------------------------------------------------------------------
__global__ __launch_bounds__(256) void out_kernel(
    const float* __restrict__ wgtbuf, const float* __restrict__ v,
    float* __restrict__ out)
{
    __shared__ float lw[8][NBAND];
    const int t  = threadIdx.x;
    const int q0 = blockIdx.x * 8;
    const int b  = blockIdx.y;

    if (t < 8 * NBAND) {
        const int qq = t / NBAND;
        const int j  = t - qq * NBAND;
        lw[qq][j] = wgtbuf[((size_t)b * LL + q0 + qq) * 32 + j];
    }
    __syncthreads();

    const int qsub = t >> 7;
    const int d4   = t & 127;
    const int qs   = q0 + qsub * 4;
    const int kbase = qs - WBAND;
    f32x4 acc[4] = {{0,0,0,0},{0,0,0,0},{0,0,0,0},{0,0,0,0}};
#pragma unroll
    for (int kk = 0; kk < 28; ++kk) {
        const int k = kbase + kk;
        f32x4 vv = {0.f, 0.f, 0.f, 0.f};
        if (k >= 0 && k < LL)
            vv = *(const f32x4*)&v[((size_t)k * BB + b) * DD + d4 * 4];
#pragma unroll
        for (int qi = 0; qi < 4; ++qi) {
            const int j = kk - qi;
            if (j >= 0 && j < NBAND) {
                const float wv = lw[qsub * 4 + qi][j];
                acc[qi][0] += wv * vv[0]; acc[qi][1] += wv * vv[1];
                acc[qi][2] += wv * vv[2]; acc[qi][3] += wv * vv[3];
            }
        }
    }
#pragma unroll
    for (int qi = 0; qi < 4; ++qi) {
        const int q = qs + qi;
        *(f32x4*)&out[((size_t)q * BB + b) * DD + d4 * 4] = acc[qi];
    }
}

// ---------------------------------------------------------------------------
extern "C" void kernel_launch(void* const* d_in, const int* in_sizes, int n_in,
                              void* d_out, int out_size, void* d_ws, size_t ws_size,
                              hipStream_t stream) {
    const float* q  = (const float*)d_in[0];
    const float* k  = (const float*)d_in[1];
    const float* v  = (const float*)d_in[2];
    const float* Wq = (const float*)d_in[3];
    const float* bq = (const float*)d_in[4];
    const float* Wk = (const float*)d_in[5];
    const float* bk = (const float*)d_in[6];

    float* out  = (float*)d_out;                       // [L,B,D]
    float* wout = out + (size_t)LL * BB * DD;          // [B,L,L]

    unsigned short* Qh = (unsigned short*)d_ws;                 // bf16 [B,H,L,DK] 8 MB
    unsigned short* Kh = Qh + (size_t)BB * HH * LL * DKK;       // bf16 8 MB
    float* Z      = (float*)(Kh + (size_t)BB * HH * LL * DKK);  // [B*H*L] 256 KB
    float* wgtbuf = Z + (size_t)BB * HH * LL;                   // [B*L][32] 1 MB

    // proj compute (x<64) + wout zero blocks (x>=64, first 40 MB)
    proj_mfma<<<dim3(64 + 32, DD / 128, 2), 256, 0, stream>>>(
        q, k, Wq, Wk, bq, bk, Qh, Kh, wout);

    // scorez compute (x<32) + wout zero blocks (x>=32, last 24 MB)
    scorez_mfma<<<dim3(32 + 8, BB * HH), 256, 0, stream>>>(Qh, Kh, Z, wout);

    weights_kernel<<<BB * LL / 4, 256, 0, stream>>>(Qh, Kh, Z, wgtbuf, wout);

    out_kernel<<<dim3(LL / 8, BB), 256, 0, stream>>>(wgtbuf, v, out);
}

// Round 12
// 130.297 us; speedup vs baseline: 1.0077x; 1.0077x over previous
//
#include <hip/hip_runtime.h>
#include <hip/hip_bf16.h>

#define LL   2048
#define BB   4
#define DD   512
#define HH   8
#define DKK  64
#define WBAND 12
#define NBAND 25   // 2*WBAND+1

typedef __attribute__((ext_vector_type(8))) short  bf16x8;
typedef __attribute__((ext_vector_type(4))) float  f32x4;

#define WOUT_F4    4194304   // B*L*L/4 total f32x4 in wout
#define ZSPLIT_F4  2621440   // f4 zeroed by proj's zero blocks (40 MB)

static __device__ __forceinline__ float bf2f(unsigned short u) {
    union { unsigned int i; float f; } c; c.i = ((unsigned int)u) << 16; return c.f;
}
static __device__ __forceinline__ unsigned short f2bf(float f) {
    union { float f; unsigned int i; } c; c.f = f;
    unsigned int x = c.i;
    return (unsigned short)((x + 0x7fffu + ((x >> 16) & 1u)) >> 16);
}
static __device__ __forceinline__ unsigned short f2bf_rn(float f) {
    __hip_bfloat16 h = __float2bfloat16(f);
    return reinterpret_cast<unsigned short&>(h);
}
static __device__ __forceinline__ bf16x8 pack8(float4 x0, float4 x1) {
    bf16x8 r;
    r[0] = (short)f2bf_rn(x0.x); r[1] = (short)f2bf_rn(x0.y);
    r[2] = (short)f2bf_rn(x0.z); r[3] = (short)f2bf_rn(x0.w);
    r[4] = (short)f2bf_rn(x1.x); r[5] = (short)f2bf_rn(x1.y);
    r[6] = (short)f2bf_rn(x1.z); r[7] = (short)f2bf_rn(x1.w);
    return r;
}

// ---------------------------------------------------------------------------
// proj: Out[b,h,l,dk] = ((X @ Wm^T)[m,n] + bias[n]) * scale.
// Compute blocks x<64; zero blocks x>=64 (NT stores: no RFO, no wave-stall
// coupling to compute blocks). grid (64+32, 4, 2).
// ---------------------------------------------------------------------------
__global__ __launch_bounds__(256) void proj_mfma(
    const float* __restrict__ Xq, const float* __restrict__ Xk,
    const float* __restrict__ Wqf, const float* __restrict__ Wkf,
    const float* __restrict__ bq, const float* __restrict__ bk,
    unsigned short* __restrict__ Qh, unsigned short* __restrict__ Kh,
    float* __restrict__ wout)
{
    __shared__ unsigned short Asm[128 * 64];
    __shared__ unsigned short Bsm[128 * 64];

    const int t = threadIdx.x;

    if (blockIdx.x >= 64) {                 // ---- zero block (NT) ----
        const int zb  = (blockIdx.z * 4 + blockIdx.y) * 32 + (blockIdx.x - 64); // 0..255
        const int gid = zb * 256 + t;                                           // 0..65535
        const f32x4 zz = {0.f, 0.f, 0.f, 0.f};
#pragma unroll
        for (int i = 0; i < 40; ++i)
            __builtin_nontemporal_store(zz,
                (f32x4*)&wout[((size_t)gid + (size_t)i * 65536) * 4]);
        return;
    }

    const int which = blockIdx.z;
    const float* X   = which ? Xk  : Xq;
    const float* Wm  = which ? Wkf : Wqf;
    const float* bias = which ? bk : bq;
    unsigned short* Out = which ? Kh : Qh;
    const float scale   = which ? 1.0f : 0.125f;

    const int w  = t >> 6;
    const int l  = t & 63;
    const int wr = w >> 1;
    const int wc = w & 1;
    const int mb = blockIdx.x * 128;
    const int nb = blockIdx.y * 128;
    const int lr = l & 15;
    const int lk = (l >> 4) * 8;

    int srow[4], scol[4], sswz[4];
#pragma unroll
    for (int i = 0; i < 4; ++i) {
        const int flat = t + i * 256;
        srow[i] = flat >> 3;
        scol[i] = (flat & 7) * 8;
        sswz[i] = (srow[i] * 64 + scol[i]) ^ ((srow[i] & 7) << 3);
    }

    float4 ra[4][2], rb[4][2];
#pragma unroll
    for (int i = 0; i < 4; ++i) {
        const float* pa = &X [(size_t)(mb + srow[i]) * DD + scol[i]];
        const float* pb = &Wm[(size_t)(nb + srow[i]) * DD + scol[i]];
        ra[i][0] = *(const float4*)pa; ra[i][1] = *(const float4*)(pa + 4);
        rb[i][0] = *(const float4*)pb; rb[i][1] = *(const float4*)(pb + 4);
    }

    f32x4 acc[4][4] = {};

    for (int k0 = 0; k0 < DD; k0 += 64) {
        __syncthreads();
#pragma unroll
        for (int i = 0; i < 4; ++i) {
            *(bf16x8*)&Asm[sswz[i]] = pack8(ra[i][0], ra[i][1]);
            *(bf16x8*)&Bsm[sswz[i]] = pack8(rb[i][0], rb[i][1]);
        }
        if (k0 + 64 < DD) {
#pragma unroll
            for (int i = 0; i < 4; ++i) {
                const float* pa = &X [(size_t)(mb + srow[i]) * DD + k0 + 64 + scol[i]];
                const float* pb = &Wm[(size_t)(nb + srow[i]) * DD + k0 + 64 + scol[i]];
                ra[i][0] = *(const float4*)pa; ra[i][1] = *(const float4*)(pa + 4);
                rb[i][0] = *(const float4*)pb; rb[i][1] = *(const float4*)(pb + 4);
            }
        }
        __syncthreads();

#pragma unroll
        for (int kk = 0; kk < 64; kk += 32) {
            bf16x8 af[4], bfr[4];
#pragma unroll
            for (int mi = 0; mi < 4; ++mi) {
                const int row = wr * 64 + 16 * mi + lr;
                af[mi] = *(const bf16x8*)&Asm[(row * 64 + kk + lk) ^ ((row & 7) << 3)];
            }
#pragma unroll
            for (int ni = 0; ni < 4; ++ni) {
                const int row = wc * 64 + 16 * ni + lr;
                bfr[ni] = *(const bf16x8*)&Bsm[(row * 64 + kk + lk) ^ ((row & 7) << 3)];
            }
#pragma unroll
            for (int mi = 0; mi < 4; ++mi)
#pragma unroll
                for (int ni = 0; ni < 4; ++ni)
                    acc[mi][ni] = __builtin_amdgcn_mfma_f32_16x16x32_bf16(
                        af[mi], bfr[ni], acc[mi][ni], 0, 0, 0);
        }
    }

#pragma unroll
    for (int ni = 0; ni < 4; ++ni) {
        const int n  = nb + wc * 64 + 16 * ni + lr;
        const int h  = n >> 6;
        const int dk = n & 63;
        const float bs = bias[n];
#pragma unroll
        for (int mi = 0; mi < 4; ++mi)
#pragma unroll
            for (int j = 0; j < 4; ++j) {
                const int m    = mb + wr * 64 + 16 * mi + (l >> 4) * 4 + j;
                const int lseq = m >> 2;
                const int bidx = m & 3;
                Out[(((size_t)(bidx * HH + h)) * LL + lseq) * DKK + dk] =
                    f2bf((acc[mi][ni][j] + bs) * scale);
            }
    }
}

// ---------------------------------------------------------------------------
// scorez: Z[bh,q] = sum_k exp( Qh[bh,q] . Kh[bh,k] )   (Q pre-scaled by 1/8)
// k-loop batched x4: 8 loads in flight, then 32 MFMA + 64 exp (ILP hides L2
// latency). Compute blocks x<32; NT zero blocks x in [32,40). grid (40, 32).
// ---------------------------------------------------------------------------
__global__ __launch_bounds__(256, 4) void scorez_mfma(
    const unsigned short* __restrict__ Qh, const unsigned short* __restrict__ Kh,
    float* __restrict__ Z, float* __restrict__ wout)
{
    __shared__ float Zp[4][64];
    const int t = threadIdx.x;

    if (blockIdx.x >= 32) {                 // ---- zero block (NT) ----
        const int zb  = blockIdx.y * 8 + (blockIdx.x - 32);   // 0..255
        const int gid = zb * 256 + t;
        const f32x4 zz = {0.f, 0.f, 0.f, 0.f};
#pragma unroll
        for (int i = 0; i < 24; ++i)
            __builtin_nontemporal_store(zz,
                (f32x4*)&wout[((size_t)ZSPLIT_F4 + (size_t)gid + (size_t)i * 65536) * 4]);
        return;
    }

    const int w  = t >> 6;
    const int l  = t & 63;
    const int bh = blockIdx.y;
    const int qb = blockIdx.x * 64;
    const int lr = l & 15;
    const int lk = (l >> 4) * 8;
    const unsigned short* Qp = Qh + (size_t)bh * LL * DKK;
    const unsigned short* Kp = Kh + (size_t)bh * LL * DKK;

    bf16x8 qa[4][2];
#pragma unroll
    for (int r = 0; r < 4; ++r)
#pragma unroll
        for (int s = 0; s < 2; ++s)
            qa[r][s] = *(const bf16x8*)&Qp[(size_t)(qb + 16 * r + lr) * DKK + 32 * s + lk];

    float zacc[4][4] = {};
    const int k0 = w * 512;

    for (int kt0 = k0; kt0 < k0 + 512; kt0 += 64) {
        bf16x8 kb[4][2];
#pragma unroll
        for (int u = 0; u < 4; ++u) {
            kb[u][0] = *(const bf16x8*)&Kp[(size_t)(kt0 + 16 * u + lr) * DKK + lk];
            kb[u][1] = *(const bf16x8*)&Kp[(size_t)(kt0 + 16 * u + lr) * DKK + 32 + lk];
        }
#pragma unroll
        for (int u = 0; u < 4; ++u)
#pragma unroll
            for (int r = 0; r < 4; ++r) {
                f32x4 acc = {0.f, 0.f, 0.f, 0.f};
                acc = __builtin_amdgcn_mfma_f32_16x16x32_bf16(qa[r][0], kb[u][0], acc, 0, 0, 0);
                acc = __builtin_amdgcn_mfma_f32_16x16x32_bf16(qa[r][1], kb[u][1], acc, 0, 0, 0);
#pragma unroll
                for (int j = 0; j < 4; ++j)
                    zacc[r][j] += __expf(acc[j]);
            }
    }

#pragma unroll
    for (int m = 8; m >= 1; m >>= 1)
#pragma unroll
        for (int r = 0; r < 4; ++r)
#pragma unroll
            for (int j = 0; j < 4; ++j)
                zacc[r][j] += __shfl_xor(zacc[r][j], m, 64);

    if (lr == 0) {
#pragma unroll
        for (int r = 0; r < 4; ++r)
#pragma unroll
            for (int j = 0; j < 4; ++j)
                Zp[w][16 * r + (l >> 4) * 4 + j] = zacc[r][j];
    }
    __syncthreads();
    if (t < 64)
        Z[(size_t)bh * LL + qb + t] = Zp[0][t] + Zp[1][t] + Zp[2][t] + Zp[3][t];
}

// ---------------------------------------------------------------------------
// weights: one WAVE per (b,q): band weights -> wgtbuf + scatter into the
// (already-zeroed) dense wout row.
// ---------------------------------------------------------------------------
__global__ __launch_bounds__(256) void weights_kernel(
    const unsigned short* __restrict__ Qh, const unsigned short* __restrict__ Kh,
    const float* __restrict__ Z, float* __restrict__ wgtbuf,
    float* __restrict__ wout)
{
    const int t = threadIdx.x;
    const int w = t >> 6;
    const int l = t & 63;
    const int idx = blockIdx.x * 4 + w;       // idx = b*L + q
    const int b = idx >> 11;
    const int q = idx & 2047;
    const int h = l >> 3;
    const int jslot = l & 7;

    bf16x8 qv[8];
    {
        const bf16x8* qp = (const bf16x8*)&Qh[(((size_t)b * HH + h) * LL + q) * DKK];
#pragma unroll
        for (int i = 0; i < 8; ++i) qv[i] = qp[i];
    }
    const float zinv = 1.0f / Z[((size_t)b * HH + h) * LL + q];

    float e[4];
#pragma unroll
    for (int c = 0; c < 4; ++c) {
        const int j = jslot + 8 * c;
        const int k = q - WBAND + j;
        float a = 0.f;
        if (j < NBAND && k >= 0 && k < LL) {
            const bf16x8* kp = (const bf16x8*)&Kh[(((size_t)b * HH + h) * LL + k) * DKK];
            float s = 0.f;
#pragma unroll
            for (int i = 0; i < 8; ++i) {
                const bf16x8 ka = kp[i];
#pragma unroll
                for (int ee = 0; ee < 8; ++ee)
                    s += bf2f((unsigned short)qv[i][ee]) * bf2f((unsigned short)ka[ee]);
            }
            a = __expf(s) * zinv;
        }
        e[c] = a;
    }

#pragma unroll
    for (int m = 8; m <= 32; m <<= 1)
#pragma unroll
        for (int c = 0; c < 4; ++c)
            e[c] += __shfl_xor(e[c], m, 64);

    float att[4];
    float part = 0.f;
#pragma unroll
    for (int c = 0; c < 4; ++c) {
        const int j = jslot + 8 * c;
        const float dd = (float)(j - WBAND);
        att[c] = (j < NBAND) ? e[c] * __expf(-0.5f * dd * dd) : 0.f;
        part += att[c];
    }
#pragma unroll
    for (int m = 1; m <= 4; m <<= 1)
        part += __shfl_xor(part, m, 64);
    const float winv = 1.0f / part;

    if (h == 0) {
        float* wrow = &wout[((size_t)b * LL + q) * LL];
#pragma unroll
        for (int c = 0; c < 4; ++c) {
            const int j = jslot + 8 * c;
            if (j < NBAND) {
                const float wv = att[c] * winv;
                wgtbuf[(size_t)idx * 32 + j] = wv;
                const int k = q - WBAND + j;
                if (k >= 0 && k < LL) wrow[k] = wv;
            }
        }
    }
}

// ---------------------------------------------------------------------------
// out: grid (L/8, B). Register sliding window over v; plain stores.
// ---------------------------------------------------------------------------
__global__ __launch_bounds__(256) void out_kernel(
    const float* __restrict__ wgtbuf, const float* __restrict__ v,
    float* __restrict__ out)
{
    __shared__ float lw[8][NBAND];
    const int t  = threadIdx.x;
    const int q0 = blockIdx.x * 8;
    const int b  = blockIdx.y;

    if (t < 8 * NBAND) {
        const int qq = t / NBAND;
        const int j  = t - qq * NBAND;
        lw[qq][j] = wgtbuf[((size_t)b * LL + q0 + qq) * 32 + j];
    }
    __syncthreads();

    const int qsub = t >> 7;
    const int d4   = t & 127;
    const int qs   = q0 + qsub * 4;
    const int kbase = qs - WBAND;
    f32x4 acc[4] = {{0,0,0,0},{0,0,0,0},{0,0,0,0},{0,0,0,0}};
#pragma unroll
    for (int kk = 0; kk < 28; ++kk) {
        const int k = kbase + kk;
        f32x4 vv = {0.f, 0.f, 0.f, 0.f};
        if (k >= 0 && k < LL)
            vv = *(const f32x4*)&v[((size_t)k * BB + b) * DD + d4 * 4];
#pragma unroll
        for (int qi = 0; qi < 4; ++qi) {
            const int j = kk - qi;
            if (j >= 0 && j < NBAND) {
                const float wv = lw[qsub * 4 + qi][j];
                acc[qi][0] += wv * vv[0]; acc[qi][1] += wv * vv[1];
                acc[qi][2] += wv * vv[2]; acc[qi][3] += wv * vv[3];
            }
        }
    }
#pragma unroll
    for (int qi = 0; qi < 4; ++qi) {
        const int q = qs + qi;
        *(f32x4*)&out[((size_t)q * BB + b) * DD + d4 * 4] = acc[qi];
    }
}

// ---------------------------------------------------------------------------
extern "C" void kernel_launch(void* const* d_in, const int* in_sizes, int n_in,
                              void* d_out, int out_size, void* d_ws, size_t ws_size,
                              hipStream_t stream) {
    const float* q  = (const float*)d_in[0];
    const float* k  = (const float*)d_in[1];
    const float* v  = (const float*)d_in[2];
    const float* Wq = (const float*)d_in[3];
    const float* bq = (const float*)d_in[4];
    const float* Wk = (const float*)d_in[5];
    const float* bk = (const float*)d_in[6];

    float* out  = (float*)d_out;                       // [L,B,D]
    float* wout = out + (size_t)LL * BB * DD;          // [B,L,L]

    unsigned short* Qh = (unsigned short*)d_ws;                 // bf16 [B,H,L,DK] 8 MB
    unsigned short* Kh = Qh + (size_t)BB * HH * LL * DKK;       // bf16 8 MB
    float* Z      = (float*)(Kh + (size_t)BB * HH * LL * DKK);  // [B*H*L] 256 KB
    float* wgtbuf = Z + (size_t)BB * HH * LL;                   // [B*L][32] 1 MB

    proj_mfma<<<dim3(64 + 32, DD / 128, 2), 256, 0, stream>>>(
        q, k, Wq, Wk, bq, bk, Qh, Kh, wout);

    scorez_mfma<<<dim3(32 + 8, BB * HH), 256, 0, stream>>>(Qh, Kh, Z, wout);

    weights_kernel<<<BB * LL / 4, 256, 0, stream>>>(Qh, Kh, Z, wgtbuf, wout);

    out_kernel<<<dim3(LL / 8, BB), 256, 0, stream>>>(wgtbuf, v, out);
}

// Round 13
// 125.471 us; speedup vs baseline: 1.0464x; 1.0385x over previous
//
#include <hip/hip_runtime.h>
#include <hip/hip_bf16.h>

#define LL   2048
#define BB   4
#define DD   512
#define HH   8
#define DKK  64
#define WBAND 12
#define NBAND 25   // 2*WBAND+1

typedef __attribute__((ext_vector_type(8))) short  bf16x8;
typedef __attribute__((ext_vector_type(4))) float  f32x4;

#define WOUT_F4    4194304   // B*L*L/4 total f32x4 in wout
#define ZSPLIT_F4  2621440   // f4 zeroed by proj's zero blocks (40 MB)

// Q pre-scale folds softmax 1/8 AND log2(e): exp(s/8) == 2^(s * 0.125*log2e)
#define QSCALE 0.18033688f
// exp(-0.5 d^2) == 2^(-0.72134752 d^2)
#define DIST_C (-0.72134752f)

static __device__ __forceinline__ float bf2f(unsigned short u) {
    union { unsigned int i; float f; } c; c.i = ((unsigned int)u) << 16; return c.f;
}
static __device__ __forceinline__ unsigned short f2bf(float f) {
    union { float f; unsigned int i; } c; c.f = f;
    unsigned int x = c.i;
    return (unsigned short)((x + 0x7fffu + ((x >> 16) & 1u)) >> 16);
}
static __device__ __forceinline__ unsigned short f2bf_rn(float f) {
    __hip_bfloat16 h = __float2bfloat16(f);
    return reinterpret_cast<unsigned short&>(h);
}
static __device__ __forceinline__ bf16x8 pack8(float4 x0, float4 x1) {
    bf16x8 r;
    r[0] = (short)f2bf_rn(x0.x); r[1] = (short)f2bf_rn(x0.y);
    r[2] = (short)f2bf_rn(x0.z); r[3] = (short)f2bf_rn(x0.w);
    r[4] = (short)f2bf_rn(x1.x); r[5] = (short)f2bf_rn(x1.y);
    r[6] = (short)f2bf_rn(x1.z); r[7] = (short)f2bf_rn(x1.w);
    return r;
}

// ---------------------------------------------------------------------------
// proj: Out[b,h,l,dk] = ((X @ Wm^T)[m,n] + bias[n]) * scale.
// Compute blocks x<64; NT zero blocks x>=64 (first 40 MB of wout).
// ---------------------------------------------------------------------------
__global__ __launch_bounds__(256) void proj_mfma(
    const float* __restrict__ Xq, const float* __restrict__ Xk,
    const float* __restrict__ Wqf, const float* __restrict__ Wkf,
    const float* __restrict__ bq, const float* __restrict__ bk,
    unsigned short* __restrict__ Qh, unsigned short* __restrict__ Kh,
    float* __restrict__ wout)
{
    __shared__ unsigned short Asm[128 * 64];
    __shared__ unsigned short Bsm[128 * 64];

    const int t = threadIdx.x;

    if (blockIdx.x >= 64) {                 // ---- zero block (NT) ----
        const int zb  = (blockIdx.z * 4 + blockIdx.y) * 32 + (blockIdx.x - 64);
        const int gid = zb * 256 + t;
        const f32x4 zz = {0.f, 0.f, 0.f, 0.f};
#pragma unroll
        for (int i = 0; i < 40; ++i)
            __builtin_nontemporal_store(zz,
                (f32x4*)&wout[((size_t)gid + (size_t)i * 65536) * 4]);
        return;
    }

    const int which = blockIdx.z;
    const float* X   = which ? Xk  : Xq;
    const float* Wm  = which ? Wkf : Wqf;
    const float* bias = which ? bk : bq;
    unsigned short* Out = which ? Kh : Qh;
    const float scale   = which ? 1.0f : QSCALE;

    const int w  = t >> 6;
    const int l  = t & 63;
    const int wr = w >> 1;
    const int wc = w & 1;
    const int mb = blockIdx.x * 128;
    const int nb = blockIdx.y * 128;
    const int lr = l & 15;
    const int lk = (l >> 4) * 8;

    int srow[4], scol[4], sswz[4];
#pragma unroll
    for (int i = 0; i < 4; ++i) {
        const int flat = t + i * 256;
        srow[i] = flat >> 3;
        scol[i] = (flat & 7) * 8;
        sswz[i] = (srow[i] * 64 + scol[i]) ^ ((srow[i] & 7) << 3);
    }

    float4 ra[4][2], rb[4][2];
#pragma unroll
    for (int i = 0; i < 4; ++i) {
        const float* pa = &X [(size_t)(mb + srow[i]) * DD + scol[i]];
        const float* pb = &Wm[(size_t)(nb + srow[i]) * DD + scol[i]];
        ra[i][0] = *(const float4*)pa; ra[i][1] = *(const float4*)(pa + 4);
        rb[i][0] = *(const float4*)pb; rb[i][1] = *(const float4*)(pb + 4);
    }

    f32x4 acc[4][4] = {};

    for (int k0 = 0; k0 < DD; k0 += 64) {
        __syncthreads();
#pragma unroll
        for (int i = 0; i < 4; ++i) {
            *(bf16x8*)&Asm[sswz[i]] = pack8(ra[i][0], ra[i][1]);
            *(bf16x8*)&Bsm[sswz[i]] = pack8(rb[i][0], rb[i][1]);
        }
        if (k0 + 64 < DD) {
#pragma unroll
            for (int i = 0; i < 4; ++i) {
                const float* pa = &X [(size_t)(mb + srow[i]) * DD + k0 + 64 + scol[i]];
                const float* pb = &Wm[(size_t)(nb + srow[i]) * DD + k0 + 64 + scol[i]];
                ra[i][0] = *(const float4*)pa; ra[i][1] = *(const float4*)(pa + 4);
                rb[i][0] = *(const float4*)pb; rb[i][1] = *(const float4*)(pb + 4);
            }
        }
        __syncthreads();

#pragma unroll
        for (int kk = 0; kk < 64; kk += 32) {
            bf16x8 af[4], bfr[4];
#pragma unroll
            for (int mi = 0; mi < 4; ++mi) {
                const int row = wr * 64 + 16 * mi + lr;
                af[mi] = *(const bf16x8*)&Asm[(row * 64 + kk + lk) ^ ((row & 7) << 3)];
            }
#pragma unroll
            for (int ni = 0; ni < 4; ++ni) {
                const int row = wc * 64 + 16 * ni + lr;
                bfr[ni] = *(const bf16x8*)&Bsm[(row * 64 + kk + lk) ^ ((row & 7) << 3)];
            }
#pragma unroll
            for (int mi = 0; mi < 4; ++mi)
#pragma unroll
                for (int ni = 0; ni < 4; ++ni)
                    acc[mi][ni] = __builtin_amdgcn_mfma_f32_16x16x32_bf16(
                        af[mi], bfr[ni], acc[mi][ni], 0, 0, 0);
        }
    }

#pragma unroll
    for (int ni = 0; ni < 4; ++ni) {
        const int n  = nb + wc * 64 + 16 * ni + lr;
        const int h  = n >> 6;
        const int dk = n & 63;
        const float bs = bias[n];
#pragma unroll
        for (int mi = 0; mi < 4; ++mi)
#pragma unroll
            for (int j = 0; j < 4; ++j) {
                const int m    = mb + wr * 64 + 16 * mi + (l >> 4) * 4 + j;
                const int lseq = m >> 2;
                const int bidx = m & 3;
                Out[(((size_t)(bidx * HH + h)) * LL + lseq) * DKK + dk] =
                    f2bf((acc[mi][ni][j] + bs) * scale);
            }
    }
}

// ---------------------------------------------------------------------------
// scorez: Z[bh,q] = sum_k 2^( Qh[bh,q] . Kh[bh,k] )  (Q pre-scaled by QSCALE)
// 2-chunk-ahead register pipeline: loads for rows [kt+32,kt+64) issue BEFORE
// the 16 MFMA + 32 exp compute of [kt,kt+32) — ~380 cyc compute covers L2
// latency; s_waitcnt lands on the end-of-iter register copies.
// Compute blocks x<32; NT zero blocks x in [32,40). grid (40, 32).
// ---------------------------------------------------------------------------
#define LDK(row, off) (*(const bf16x8*)&Kp[(size_t)((row) + lr) * DKK + (off) + lk])

__global__ __launch_bounds__(256) void scorez_mfma(
    const unsigned short* __restrict__ Qh, const unsigned short* __restrict__ Kh,
    float* __restrict__ Z, float* __restrict__ wout)
{
    __shared__ float Zp[4][64];
    const int t = threadIdx.x;

    if (blockIdx.x >= 32) {                 // ---- zero block (NT) ----
        const int zb  = blockIdx.y * 8 + (blockIdx.x - 32);
        const int gid = zb * 256 + t;
        const f32x4 zz = {0.f, 0.f, 0.f, 0.f};
#pragma unroll
        for (int i = 0; i < 24; ++i)
            __builtin_nontemporal_store(zz,
                (f32x4*)&wout[((size_t)ZSPLIT_F4 + (size_t)gid + (size_t)i * 65536) * 4]);
        return;
    }

    const int w  = t >> 6;
    const int l  = t & 63;
    const int bh = blockIdx.y;
    const int qb = blockIdx.x * 64;
    const int lr = l & 15;
    const int lk = (l >> 4) * 8;
    const unsigned short* Qp = Qh + (size_t)bh * LL * DKK;
    const unsigned short* Kp = Kh + (size_t)bh * LL * DKK;

    bf16x8 qa[4][2];
#pragma unroll
    for (int r = 0; r < 4; ++r)
#pragma unroll
        for (int s = 0; s < 2; ++s)
            qa[r][s] = *(const bf16x8*)&Qp[(size_t)(qb + 16 * r + lr) * DKK + 32 * s + lk];

    float zacc[4][4] = {};
    const int k0 = w * 512;

    // prologue: preload chunks [k0, k0+16) and [k0+16, k0+32)
    bf16x8 a0 = LDK(k0, 0),      a1 = LDK(k0, 32);
    bf16x8 b0 = LDK(k0 + 16, 0), b1 = LDK(k0 + 16, 32);

    for (int kt = k0; kt < k0 + 512; kt += 32) {
        bf16x8 na0, na1, nb0, nb1;
        const bool has = (kt + 32) < (k0 + 512);
        if (has) {
            na0 = LDK(kt + 32, 0); na1 = LDK(kt + 32, 32);
            nb0 = LDK(kt + 48, 0); nb1 = LDK(kt + 48, 32);
        }
#pragma unroll
        for (int r = 0; r < 4; ++r) {
            f32x4 acc = {0.f, 0.f, 0.f, 0.f};
            acc = __builtin_amdgcn_mfma_f32_16x16x32_bf16(qa[r][0], a0, acc, 0, 0, 0);
            acc = __builtin_amdgcn_mfma_f32_16x16x32_bf16(qa[r][1], a1, acc, 0, 0, 0);
#pragma unroll
            for (int j = 0; j < 4; ++j)
                zacc[r][j] += __builtin_amdgcn_exp2f(acc[j]);
        }
#pragma unroll
        for (int r = 0; r < 4; ++r) {
            f32x4 acc = {0.f, 0.f, 0.f, 0.f};
            acc = __builtin_amdgcn_mfma_f32_16x16x32_bf16(qa[r][0], b0, acc, 0, 0, 0);
            acc = __builtin_amdgcn_mfma_f32_16x16x32_bf16(qa[r][1], b1, acc, 0, 0, 0);
#pragma unroll
            for (int j = 0; j < 4; ++j)
                zacc[r][j] += __builtin_amdgcn_exp2f(acc[j]);
        }
        if (has) { a0 = na0; a1 = na1; b0 = nb0; b1 = nb1; }
    }

#pragma unroll
    for (int m = 8; m >= 1; m >>= 1)
#pragma unroll
        for (int r = 0; r < 4; ++r)
#pragma unroll
            for (int j = 0; j < 4; ++j)
                zacc[r][j] += __shfl_xor(zacc[r][j], m, 64);

    if (lr == 0) {
#pragma unroll
        for (int r = 0; r < 4; ++r)
#pragma unroll
            for (int j = 0; j < 4; ++j)
                Zp[w][16 * r + (l >> 4) * 4 + j] = zacc[r][j];
    }
    __syncthreads();
    if (t < 64)
        Z[(size_t)bh * LL + qb + t] = Zp[0][t] + Zp[1][t] + Zp[2][t] + Zp[3][t];
}

// ---------------------------------------------------------------------------
// weights: one WAVE per (b,q): band weights -> wgtbuf + scatter into the
// (already-zeroed) dense wout row. Uses exp2 consistently with scorez.
// ---------------------------------------------------------------------------
__global__ __launch_bounds__(256) void weights_kernel(
    const unsigned short* __restrict__ Qh, const unsigned short* __restrict__ Kh,
    const float* __restrict__ Z, float* __restrict__ wgtbuf,
    float* __restrict__ wout)
{
    const int t = threadIdx.x;
    const int w = t >> 6;
    const int l = t & 63;
    const int idx = blockIdx.x * 4 + w;       // idx = b*L + q
    const int b = idx >> 11;
    const int q = idx & 2047;
    const int h = l >> 3;
    const int jslot = l & 7;

    bf16x8 qv[8];
    {
        const bf16x8* qp = (const bf16x8*)&Qh[(((size_t)b * HH + h) * LL + q) * DKK];
#pragma unroll
        for (int i = 0; i < 8; ++i) qv[i] = qp[i];
    }
    const float zinv = 1.0f / Z[((size_t)b * HH + h) * LL + q];

    float e[4];
#pragma unroll
    for (int c = 0; c < 4; ++c) {
        const int j = jslot + 8 * c;
        const int k = q - WBAND + j;
        float a = 0.f;
        if (j < NBAND && k >= 0 && k < LL) {
            const bf16x8* kp = (const bf16x8*)&Kh[(((size_t)b * HH + h) * LL + k) * DKK];
            float s = 0.f;
#pragma unroll
            for (int i = 0; i < 8; ++i) {
                const bf16x8 ka = kp[i];
#pragma unroll
                for (int ee = 0; ee < 8; ++ee)
                    s += bf2f((unsigned short)qv[i][ee]) * bf2f((unsigned short)ka[ee]);
            }
            a = __builtin_amdgcn_exp2f(s) * zinv;
        }
        e[c] = a;
    }

#pragma unroll
    for (int m = 8; m <= 32; m <<= 1)
#pragma unroll
        for (int c = 0; c < 4; ++c)
            e[c] += __shfl_xor(e[c], m, 64);

    float att[4];
    float part = 0.f;
#pragma unroll
    for (int c = 0; c < 4; ++c) {
        const int j = jslot + 8 * c;
        const float dd = (float)(j - WBAND);
        att[c] = (j < NBAND) ? e[c] * __builtin_amdgcn_exp2f(DIST_C * dd * dd) : 0.f;
        part += att[c];
    }
#pragma unroll
    for (int m = 1; m <= 4; m <<= 1)
        part += __shfl_xor(part, m, 64);
    const float winv = 1.0f / part;

    if (h == 0) {
        float* wrow = &wout[((size_t)b * LL + q) * LL];
#pragma unroll
        for (int c = 0; c < 4; ++c) {
            const int j = jslot + 8 * c;
            if (j < NBAND) {
                const float wv = att[c] * winv;
                wgtbuf[(size_t)idx * 32 + j] = wv;
                const int k = q - WBAND + j;
                if (k >= 0 && k < LL) wrow[k] = wv;
            }
        }
    }
}

// ---------------------------------------------------------------------------
// out: grid (L/8, B). Register sliding window over v; plain stores.
// ---------------------------------------------------------------------------
__global__ __launch_bounds__(256) void out_kernel(
    const float* __restrict__ wgtbuf, const float* __restrict__ v,
    float* __restrict__ out)
{
    __shared__ float lw[8][NBAND];
    const int t  = threadIdx.x;
    const int q0 = blockIdx.x * 8;
    const int b  = blockIdx.y;

    if (t < 8 * NBAND) {
        const int qq = t / NBAND;
        const int j  = t - qq * NBAND;
        lw[qq][j] = wgtbuf[((size_t)b * LL + q0 + qq) * 32 + j];
    }
    __syncthreads();

    const int qsub = t >> 7;
    const int d4   = t & 127;
    const int qs   = q0 + qsub * 4;
    const int kbase = qs - WBAND;
    f32x4 acc[4] = {{0,0,0,0},{0,0,0,0},{0,0,0,0},{0,0,0,0}};
#pragma unroll
    for (int kk = 0; kk < 28; ++kk) {
        const int k = kbase + kk;
        f32x4 vv = {0.f, 0.f, 0.f, 0.f};
        if (k >= 0 && k < LL)
            vv = *(const f32x4*)&v[((size_t)k * BB + b) * DD + d4 * 4];
#pragma unroll
        for (int qi = 0; qi < 4; ++qi) {
            const int j = kk - qi;
            if (j >= 0 && j < NBAND) {
                const float wv = lw[qsub * 4 + qi][j];
                acc[qi][0] += wv * vv[0]; acc[qi][1] += wv * vv[1];
                acc[qi][2] += wv * vv[2]; acc[qi][3] += wv * vv[3];
            }
        }
    }
#pragma unroll
    for (int qi = 0; qi < 4; ++qi) {
        const int q = qs + qi;
        *(f32x4*)&out[((size_t)q * BB + b) * DD + d4 * 4] = acc[qi];
    }
}

// ---------------------------------------------------------------------------
extern "C" void kernel_launch(void* const* d_in, const int* in_sizes, int n_in,
                              void* d_out, int out_size, void* d_ws, size_t ws_size,
                              hipStream_t stream) {
    const float* q  = (const float*)d_in[0];
    const float* k  = (const float*)d_in[1];
    const float* v  = (const float*)d_in[2];
    const float* Wq = (const float*)d_in[3];
    const float* bq = (const float*)d_in[4];
    const float* Wk = (const float*)d_in[5];
    const float* bk = (const float*)d_in[6];

    float* out  = (float*)d_out;                       // [L,B,D]
    float* wout = out + (size_t)LL * BB * DD;          // [B,L,L]

    unsigned short* Qh = (unsigned short*)d_ws;                 // bf16 [B,H,L,DK] 8 MB
    unsigned short* Kh = Qh + (size_t)BB * HH * LL * DKK;       // bf16 8 MB
    float* Z      = (float*)(Kh + (size_t)BB * HH * LL * DKK);  // [B*H*L] 256 KB
    float* wgtbuf = Z + (size_t)BB * HH * LL;                   // [B*L][32] 1 MB

    proj_mfma<<<dim3(64 + 32, DD / 128, 2), 256, 0, stream>>>(
        q, k, Wq, Wk, bq, bk, Qh, Kh, wout);

    scorez_mfma<<<dim3(32 + 8, BB * HH), 256, 0, stream>>>(Qh, Kh, Z, wout);

    weights_kernel<<<BB * LL / 4, 256, 0, stream>>>(Qh, Kh, Z, wgtbuf, wout);

    out_kernel<<<dim3(LL / 8, BB), 256, 0, stream>>>(wgtbuf, v, out);
}